// Round 11
// baseline (339.226 us; speedup 1.0000x reference)
//
#include <hip/hip_runtime.h>
#include <stdint.h>

#define N_NODES 40000
#define N_EDGES 1280000
#define NODE_BLOCKS 625   // ceil(40000/64)

typedef __attribute__((ext_vector_type(8))) short bf16x8;   // 8 bf16 in 4 VGPRs
typedef __attribute__((ext_vector_type(4))) float f32x4;    // MFMA C/D
typedef __attribute__((ext_vector_type(2))) _Float16 f16x2;

#define MFMA16(a, b, c) __builtin_amdgcn_mfma_f32_16x16x32_bf16((a), (b), (c), 0, 0, 0)

#if defined(__has_builtin)
#if __has_builtin(__builtin_amdgcn_cvt_pk_bf16_f32)
#define HAS_CVT_PK_BF16 1
#endif
#endif

// ---------- helpers ----------
__device__ __forceinline__ float fast_silu(float x) {
    float e = __expf(-x);
    return x * __builtin_amdgcn_rcpf(1.0f + e);
}

__device__ __forceinline__ unsigned short f2bf(float x) {
    unsigned int u = __float_as_uint(x);
    u = (u + 0x7FFFu + ((u >> 16) & 1u)) >> 16;
    return (unsigned short)u;
}

__device__ __forceinline__ unsigned int pack_bf2(float a, float b) {
#ifdef HAS_CVT_PK_BF16
    typedef __attribute__((ext_vector_type(2))) __bf16 bf2_t;
    bf2_t r = __builtin_amdgcn_cvt_pk_bf16_f32(a, b);   // low = a, high = b, RNE
    return __builtin_bit_cast(unsigned int, r);
#else
    unsigned int ua = __float_as_uint(a);
    unsigned int ub = __float_as_uint(b);
    ua = (ua + 0x7FFFu + ((ua >> 16) & 1u)) >> 16;
    ub = (ub + 0x7FFFu + ((ub >> 16) & 1u)) & 0xFFFF0000u;
    return (ua & 0xFFFFu) | ub;
#endif
}

__device__ __forceinline__ float bf16_to_f(unsigned short s) {
    return __uint_as_float(((unsigned int)s) << 16);
}

__device__ __forceinline__ unsigned int pk_f16(float a, float b) {
    f16x2 v; v.x = (_Float16)a; v.y = (_Float16)b;
    return __builtin_bit_cast(unsigned int, v);
}
__device__ __forceinline__ float f16_lo(unsigned int u) {
    f16x2 v = __builtin_bit_cast(f16x2, u); return (float)v.x;
}
__device__ __forceinline__ float f16_hi(unsigned int u) {
    f16x2 v = __builtin_bit_cast(f16x2, u); return (float)v.y;
}

// ============================================================================
// k1: hist + rank (atomic return = in-row rank) + coord4 + weight packing
// ============================================================================
__global__ void hist_rank_kernel(const int* __restrict__ eidx, const float* __restrict__ coord,
                                 const float* __restrict__ We1, const float* __restrict__ We2,
                                 const float* __restrict__ Wc1, const float* __restrict__ Wn1,
                                 const float* __restrict__ Wn2,
                                 int* __restrict__ hist, int* __restrict__ rank,
                                 float4* __restrict__ coord4,
                                 unsigned short* __restrict__ Wt1, unsigned short* __restrict__ Wt2,
                                 unsigned short* __restrict__ Wtc1, unsigned short* __restrict__ Wtn1,
                                 unsigned short* __restrict__ Wtn2)
{
    const int b = blockIdx.x;
    if (b < 1250) {
        const int i = (b * 256 + threadIdx.x) * 4;
        const int4 r = *(const int4*)(eidx + i);
        int4 k;
        k.x = atomicAdd(&hist[r.x], 1);
        k.y = atomicAdd(&hist[r.y], 1);
        k.z = atomicAdd(&hist[r.z], 1);
        k.w = atomicAdd(&hist[r.w], 1);
        *(int4*)(rank + i) = k;
    } else if (b < 1407) {
        const int n = (b - 1250) * 256 + threadIdx.x;
        if (n < N_NODES)
            coord4[n] = make_float4(coord[n * 3 + 0], coord[n * 3 + 1], coord[n * 3 + 2], 0.f);
    } else {
        const int t = (b - 1407) * 256 + threadIdx.x;
        if (t < 8192)       { Wt1[t]  = f2bf(We1[(t & 127) * 64 + (t >> 7)]); }
        else if (t < 12288) { int u = t - 8192;  Wt2[u]  = f2bf(We2[(u & 63) * 64 + (u >> 6)]); }
        else if (t < 16384) { int u = t - 12288; Wtc1[u] = f2bf(Wc1[(u & 63) * 64 + (u >> 6)]); }
        else if (t < 24576) { int u = t - 16384; Wtn1[u] = f2bf(Wn1[(u & 127) * 64 + (u >> 7)]); }
        else if (t < 28672) { int u = t - 24576; Wtn2[u] = f2bf(Wn2[(u & 63) * 64 + (u >> 6)]); }
    }
}

// ============================================================================
// k2: single-block scan (offs only)
// ============================================================================
__global__ __launch_bounds__(1024) void scan_kernel(const int* __restrict__ hist,
                                                    int* __restrict__ offs) {
    __shared__ int wtot[16];
    __shared__ int carry_s;
    const int t = threadIdx.x;
    const int wave = t >> 6, lane = t & 63;
    if (t == 0) carry_s = 0;
    __syncthreads();
    for (int base = 0; base < N_NODES; base += 8192) {
        const int idx = base + t * 8;
        int v[8];
        if (idx + 8 <= N_NODES) {
            const int4 a = *(const int4*)(hist + idx);
            const int4 b = *(const int4*)(hist + idx + 4);
            v[0] = a.x; v[1] = a.y; v[2] = a.z; v[3] = a.w;
            v[4] = b.x; v[5] = b.y; v[6] = b.z; v[7] = b.w;
        } else {
            #pragma unroll
            for (int j = 0; j < 8; ++j) v[j] = (idx + j < N_NODES) ? hist[idx + j] : 0;
        }
        int s = 0;
        #pragma unroll
        for (int j = 0; j < 8; ++j) s += v[j];
        int S = s;
        #pragma unroll
        for (int d = 1; d < 64; d <<= 1) {
            const int u = __shfl_up(S, d, 64);
            if (lane >= d) S += u;
        }
        if (lane == 63) wtot[wave] = S;
        __syncthreads();
        if (wave == 0 && lane < 16) {
            int w = wtot[lane];
            #pragma unroll
            for (int d = 1; d < 16; d <<= 1) {
                const int u = __shfl_up(w, d, 64);
                if (lane >= d) w += u;
            }
            wtot[lane] = w;
        }
        __syncthreads();
        const int wb = (wave == 0) ? 0 : wtot[wave - 1];
        int run = carry_s + wb + (S - s);
        #pragma unroll
        for (int j = 0; j < 8; ++j) {
            if (idx + j < N_NODES) offs[idx + j] = run;
            run += v[j];
        }
        __syncthreads();
        if (t == 0) carry_s += wtot[15];
        __syncthreads();
    }
}

// ============================================================================
// k3: scatter (slot = offs[r] + rank[e], no atomics) + h pack + agg zero
// ============================================================================
__global__ void scatter_prep_kernel(const int* __restrict__ eidx, const float* __restrict__ emask,
                                    const int* __restrict__ rank, const int* __restrict__ offs,
                                    const float4* __restrict__ coord4,
                                    uint4* __restrict__ payload,
                                    const float* __restrict__ h,
                                    unsigned short* __restrict__ h_bf,
                                    float* __restrict__ aggz)
{
    const int b = blockIdx.x;
    if (b < 1250) {
        const int i = (b * 256 + threadIdx.x) * 4;
        const int4 r = *(const int4*)(eidx + i);
        const int4 c = *(const int4*)(eidx + N_EDGES + i);
        const float4 mk = *(const float4*)(emask + i);
        const int4 k = *(const int4*)(rank + i);
        #pragma unroll
        for (int j = 0; j < 4; ++j) {
            const int rj = (&r.x)[j], cj = (&c.x)[j];
            const float4 cr = coord4[rj];
            const float4 cc = coord4[cj];
            const float d0 = cr.x - cc.x, d1 = cr.y - cc.y, d2 = cr.z - cc.z;
            const float rad = d0 * d0 + d1 * d1 + d2 * d2;
            const int slot = offs[rj] + (&k.x)[j];
            payload[slot] = make_uint4((unsigned)rj | ((unsigned)cj << 16),
                                       pk_f16(d0, d1), pk_f16(d2, (&mk.x)[j]),
                                       __float_as_uint(rad));
        }
    } else if (b < 3750) {
        const int i = ((b - 1250) * 256 + threadIdx.x) * 4;   // exactly covers 2,560,000
        const float4 v = *(const float4*)(h + i);
        *(uint2*)(h_bf + i) = make_uint2(pack_bf2(v.x, v.y), pack_bf2(v.z, v.w));
    } else {
        const int i = ((b - 3750) * 256 + threadIdx.x) * 4;
        if (i < N_NODES * 67)
            *(float4*)(aggz + i) = make_float4(0.f, 0.f, 0.f, 0.f);
    }
}

// ============================================================================
// k4: edge kernel — layer-1 fragments loaded DIRECTLY from global (no LDS
// staging); A tile used only for m1/m. LDS = 40960 B -> 4 blocks/CU.
// ============================================================================
__global__ __launch_bounds__(256, 4) void egcl_edge_mfma(
    const unsigned short* __restrict__ h_bf,
    const uint4* __restrict__ payload,
    const int* __restrict__ offs_g, const int* __restrict__ hist_g,
    const float* __restrict__ We1, const float* __restrict__ be1,
    const float* __restrict__ be2, const float* __restrict__ bc1,
    const float* __restrict__ Wc2,
    const unsigned short* __restrict__ Wt1, const unsigned short* __restrict__ Wt2,
    const unsigned short* __restrict__ Wtc1,
    float* __restrict__ agg, float* __restrict__ aggc)
{
    __shared__ __align__(16) unsigned short A[256 * 72];
    __shared__ float dif_s[768];
    __shared__ float cval_s[256];

    const int t = threadIdx.x;
    const int w = t >> 6, L = t & 63;
    const int q = L >> 4, lc = L & 15;
    const int ebase = blockIdx.x * 256;
    const int rbase = w * 64;

    // ---- meta: ONE coalesced 16B payload read ----
    int my_r, my_c;
    float my_rad, my_msk;
    {
        const uint4 pl = payload[ebase + t];
        my_r = (int)(pl.x & 0xFFFFu);
        my_c = (int)(pl.x >> 16);
        const float d0 = f16_lo(pl.y);
        const float d1 = f16_hi(pl.y);
        const float d2 = f16_lo(pl.z);
        my_msk = f16_hi(pl.z);
        my_rad = __uint_as_float(pl.w);
        dif_s[t * 3 + 0] = d0; dif_s[t * 3 + 1] = d1; dif_s[t * 3 + 2] = d2;
        if (t == 0)   *(int*)&A[64] = my_r;   // n0 in row-0 padding
        if (t == 255) *(int*)&A[66] = my_r;   // n1
    }

    // per-et indices / rad / mask via shfl (slot et*16+lc is in this wave)
    int r_et[4], c_et[4];
    float rad_et[4], mk_et[4];
    #pragma unroll
    for (int et = 0; et < 4; ++et) {
        const int sl = et * 16 + lc;
        r_et[et]   = __shfl(my_r, sl, 64);
        c_et[et]   = __shfl(my_c, sl, 64);
        rad_et[et] = __shfl(my_rad, sl, 64);
        mk_et[et]  = __shfl(my_msk, sl, 64);
    }

    // ---- layer1 init ----
    f32x4 acc[4][4];   // [ot][et]
    #pragma unroll
    for (int ot = 0; ot < 4; ++ot) {
        const float4 bv = *(const float4*)(be1 + ot * 16 + q * 4);
        const float4 wv = *(const float4*)(We1 + 128 * 64 + ot * 16 + q * 4);
        #pragma unroll
        for (int et = 0; et < 4; ++et) {
            const float rad = rad_et[et];
            acc[ot][et][0] = fmaf(rad, wv.x, bv.x);
            acc[ot][et][1] = fmaf(rad, wv.y, bv.y);
            acc[ot][et][2] = fmaf(rad, wv.z, bv.z);
            acc[ot][et][3] = fmaf(rad, wv.w, bv.w);
        }
    }

    // ---- layer1 MFMA, k = 0..63 (h[row]) — fragments direct from global ----
    #pragma unroll
    for (int ks = 0; ks < 2; ++ks) {
        bf16x8 bfr[4];
        #pragma unroll
        for (int et = 0; et < 4; ++et)
            bfr[et] = *(const bf16x8*)(h_bf + (size_t)r_et[et] * 64 + ks * 32 + q * 8);
        #pragma unroll
        for (int ot = 0; ot < 4; ++ot) {
            const bf16x8 af = *(const bf16x8*)&Wt1[(ot * 16 + lc) * 128 + ks * 32 + q * 8];
            #pragma unroll
            for (int et = 0; et < 4; ++et)
                acc[ot][et] = MFMA16(af, bfr[et], acc[ot][et]);
        }
    }

    // ---- layer1 MFMA, k = 64..127 (h[col]) — fragments direct from global ----
    #pragma unroll
    for (int ks = 0; ks < 2; ++ks) {
        bf16x8 bfr[4];
        #pragma unroll
        for (int et = 0; et < 4; ++et)
            bfr[et] = *(const bf16x8*)(h_bf + (size_t)c_et[et] * 64 + ks * 32 + q * 8);
        #pragma unroll
        for (int ot = 0; ot < 4; ++ot) {
            const bf16x8 af = *(const bf16x8*)&Wt1[(ot * 16 + lc) * 128 + 64 + ks * 32 + q * 8];
            #pragma unroll
            for (int et = 0; et < 4; ++et)
                acc[ot][et] = MFMA16(af, bfr[et], acc[ot][et]);
        }
    }

    // ---- m1 = silu -> A (A first used here) ----
    #pragma unroll
    for (int et = 0; et < 4; ++et) {
        const int row = rbase + et * 16 + lc;
        #pragma unroll
        for (int ot = 0; ot < 4; ++ot) {
            uint2 p;
            p.x = pack_bf2(fast_silu(acc[ot][et][0]), fast_silu(acc[ot][et][1]));
            p.y = pack_bf2(fast_silu(acc[ot][et][2]), fast_silu(acc[ot][et][3]));
            *(uint2*)&A[row * 72 + ot * 16 + q * 4] = p;
        }
    }

    // ---- layer2 ----
    f32x4 acc2[4][4];
    #pragma unroll
    for (int ot = 0; ot < 4; ++ot) {
        const float4 bv = *(const float4*)(be2 + ot * 16 + q * 4);
        #pragma unroll
        for (int et = 0; et < 4; ++et) {
            acc2[ot][et][0] = bv.x; acc2[ot][et][1] = bv.y;
            acc2[ot][et][2] = bv.z; acc2[ot][et][3] = bv.w;
        }
    }
    #pragma unroll
    for (int ks = 0; ks < 2; ++ks) {
        bf16x8 bfr[4];
        #pragma unroll
        for (int et = 0; et < 4; ++et)
            bfr[et] = *(const bf16x8*)&A[(rbase + et * 16 + lc) * 72 + ks * 32 + q * 8];
        #pragma unroll
        for (int ot = 0; ot < 4; ++ot) {
            const bf16x8 af = *(const bf16x8*)&Wt2[(ot * 16 + lc) * 64 + ks * 32 + q * 8];
            #pragma unroll
            for (int et = 0; et < 4; ++et)
                acc2[ot][et] = MFMA16(af, bfr[et], acc2[ot][et]);
        }
    }

    // ---- m = silu * mask -> A ----
    #pragma unroll
    for (int et = 0; et < 4; ++et) {
        const int row = rbase + et * 16 + lc;
        const float mk = mk_et[et];
        #pragma unroll
        for (int ot = 0; ot < 4; ++ot) {
            uint2 p;
            p.x = pack_bf2(fast_silu(acc2[ot][et][0]) * mk, fast_silu(acc2[ot][et][1]) * mk);
            p.y = pack_bf2(fast_silu(acc2[ot][et][2]) * mk, fast_silu(acc2[ot][et][3]) * mk);
            *(uint2*)&A[row * 72 + ot * 16 + q * 4] = p;
        }
    }

    // ---- coord mlp ----
    f32x4 acc3[4][4];
    #pragma unroll
    for (int ot = 0; ot < 4; ++ot) {
        const float4 bv = *(const float4*)(bc1 + ot * 16 + q * 4);
        #pragma unroll
        for (int et = 0; et < 4; ++et) {
            acc3[ot][et][0] = bv.x; acc3[ot][et][1] = bv.y;
            acc3[ot][et][2] = bv.z; acc3[ot][et][3] = bv.w;
        }
    }
    #pragma unroll
    for (int ks = 0; ks < 2; ++ks) {
        bf16x8 bfr[4];
        #pragma unroll
        for (int et = 0; et < 4; ++et)
            bfr[et] = *(const bf16x8*)&A[(rbase + et * 16 + lc) * 72 + ks * 32 + q * 8];
        #pragma unroll
        for (int ot = 0; ot < 4; ++ot) {
            const bf16x8 af = *(const bf16x8*)&Wtc1[(ot * 16 + lc) * 64 + ks * 32 + q * 8];
            #pragma unroll
            for (int et = 0; et < 4; ++et)
                acc3[ot][et] = MFMA16(af, bfr[et], acc3[ot][et]);
        }
    }
    {
        float4 wv[4];
        #pragma unroll
        for (int ot = 0; ot < 4; ++ot) wv[ot] = *(const float4*)(Wc2 + ot * 16 + q * 4);
        #pragma unroll
        for (int et = 0; et < 4; ++et) {
            float s = 0.0f;
            #pragma unroll
            for (int ot = 0; ot < 4; ++ot) {
                s = fmaf(fast_silu(acc3[ot][et][0]), wv[ot].x, s);
                s = fmaf(fast_silu(acc3[ot][et][1]), wv[ot].y, s);
                s = fmaf(fast_silu(acc3[ot][et][2]), wv[ot].z, s);
                s = fmaf(fast_silu(acc3[ot][et][3]), wv[ot].w, s);
            }
            s += __shfl_xor(s, 16, 64);
            s += __shfl_xor(s, 32, 64);
            if (q == 0)
                cval_s[rbase + et * 16 + lc] = s * mk_et[et];
        }
    }

    __syncthreads();   // whole block's m / cval / dif now valid

    // ---- fused segmented aggregation ----
    {
        const int n0 = *(const int*)&A[64];
        const int n1 = *(const int*)&A[66];
        for (int n = n0 + w; n <= n1; n += 4) {
            const int os = offs_g[n];
            const int dg = hist_g[n];
            const int s0 = max(os - ebase, 0);
            const int s1 = min(os + dg - ebase, 256);
            float s = 0.0f, t3 = 0.0f;
            const bool c3 = (L < 3);
            int slot = s0;
            for (; slot + 4 <= s1; slot += 4) {
                const float a0 = bf16_to_f(A[(slot + 0) * 72 + L]);
                const float a1 = bf16_to_f(A[(slot + 1) * 72 + L]);
                const float a2 = bf16_to_f(A[(slot + 2) * 72 + L]);
                const float a3 = bf16_to_f(A[(slot + 3) * 72 + L]);
                s += (a0 + a1) + (a2 + a3);
                if (c3) {
                    t3 = fmaf(dif_s[(slot + 0) * 3 + L], cval_s[slot + 0], t3);
                    t3 = fmaf(dif_s[(slot + 1) * 3 + L], cval_s[slot + 1], t3);
                    t3 = fmaf(dif_s[(slot + 2) * 3 + L], cval_s[slot + 2], t3);
                    t3 = fmaf(dif_s[(slot + 3) * 3 + L], cval_s[slot + 3], t3);
                }
            }
            for (; slot < s1; ++slot) {
                s += bf16_to_f(A[slot * 72 + L]);
                if (c3) t3 = fmaf(dif_s[slot * 3 + L], cval_s[slot], t3);
            }
            const bool interior = (os >= ebase) && (os + dg <= ebase + 256);
            if (interior) {
                agg[(size_t)n * 64 + L] = s;
                if (c3) aggc[n * 3 + L] = t3;
            } else {
                atomicAdd(&agg[(size_t)n * 64 + L], s);
                if (c3) atomicAdd(&aggc[n * 3 + L], t3);
            }
        }
    }
}

// ============================================================================
// k5: node MLP (64 nodes/block -> grid 625, kills dispatch tail) + coord out
// ============================================================================
__global__ __launch_bounds__(256, 4) void egcl_node_coord(
    const unsigned short* __restrict__ h_bf, const float* __restrict__ agg,
    const float* __restrict__ bn1, const float* __restrict__ bn2,
    const unsigned short* __restrict__ Wtn1, const unsigned short* __restrict__ Wtn2,
    const float* __restrict__ coord, const float* __restrict__ aggc,
    const int* __restrict__ hist,
    float* __restrict__ hout, float* __restrict__ cout)
{
    if (blockIdx.x >= NODE_BLOCKS) {
        const int i = (blockIdx.x - NODE_BLOCKS) * 256 + threadIdx.x;
        if (i < N_NODES * 3) {
            const int node = i / 3;
            const float c = fmaxf((float)hist[node], 1.0f);
            cout[i] = coord[i] + aggc[i] * __builtin_amdgcn_rcpf(c);
        }
        return;
    }

    __shared__ __align__(16) unsigned short A[64 * 136];   // 17408 B
    const int t = threadIdx.x;
    const int wave = t >> 6, L = t & 63;
    const int q = L >> 4, lc = L & 15;
    const int nbase = blockIdx.x * 64;
    const int rbase = wave * 16;   // wave owns one 16-row tile

    // stage h_bf (k 0..63) + bf16(agg) (k 64..127): 64 rows x 32 8B-parts
    #pragma unroll
    for (int it = 0; it < 8; ++it) {
        const int idx = it * 256 + t;
        const int ln = idx >> 5, part = idx & 31;
        const int node = nbase + ln;
        uint2 u = make_uint2(0u, 0u);
        if (node < N_NODES) {
            if (part < 16) {
                u = *(const uint2*)(h_bf + (size_t)node * 64 + part * 4);
            } else {
                const float4 v = *(const float4*)(agg + (size_t)node * 64 + (part - 16) * 4);
                u = make_uint2(pack_bf2(v.x, v.y), pack_bf2(v.z, v.w));
            }
        }
        *(uint2*)&A[ln * 136 + part * 4] = u;
    }
    __syncthreads();

    f32x4 acc1[4];
    #pragma unroll
    for (int ct = 0; ct < 4; ++ct) {
        const float b = bn1[ct * 16 + lc];
        #pragma unroll
        for (int i = 0; i < 4; ++i) acc1[ct][i] = b;
    }
    #pragma unroll
    for (int ks = 0; ks < 4; ++ks) {
        const bf16x8 af = *(const bf16x8*)&A[(rbase + lc) * 136 + ks * 32 + q * 8];
        #pragma unroll
        for (int ct = 0; ct < 4; ++ct) {
            const bf16x8 bf = *(const bf16x8*)&Wtn1[(ct * 16 + lc) * 128 + ks * 32 + q * 8];
            acc1[ct] = MFMA16(af, bf, acc1[ct]);
        }
    }
    __syncthreads();

    #pragma unroll
    for (int ct = 0; ct < 4; ++ct)
        #pragma unroll
        for (int i = 0; i < 4; ++i) {
            const int row = rbase + q * 4 + i;
            A[row * 72 + ct * 16 + lc] = f2bf(fast_silu(acc1[ct][i]));
        }
    __syncthreads();

    f32x4 acc2[4];
    #pragma unroll
    for (int ct = 0; ct < 4; ++ct) {
        const float b = bn2[ct * 16 + lc];
        #pragma unroll
        for (int i = 0; i < 4; ++i) acc2[ct][i] = b;
    }
    #pragma unroll
    for (int ks = 0; ks < 2; ++ks) {
        const bf16x8 af = *(const bf16x8*)&A[(rbase + lc) * 72 + ks * 32 + q * 8];
        #pragma unroll
        for (int ct = 0; ct < 4; ++ct) {
            const bf16x8 bf = *(const bf16x8*)&Wtn2[(ct * 16 + lc) * 64 + ks * 32 + q * 8];
            acc2[ct] = MFMA16(af, bf, acc2[ct]);
        }
    }

    #pragma unroll
    for (int ct = 0; ct < 4; ++ct)
        #pragma unroll
        for (int i = 0; i < 4; ++i) {
            const int node = nbase + rbase + q * 4 + i;
            if (node < N_NODES)
                hout[(size_t)node * 64 + ct * 16 + lc] = acc2[ct][i];
        }
}

// ============================================================================
// launch
// ============================================================================
extern "C" void kernel_launch(void* const* d_in, const int* in_sizes, int n_in,
                              void* d_out, int out_size, void* d_ws, size_t ws_size,
                              hipStream_t stream)
{
    const float* h     = (const float*)d_in[0];
    const float* coord = (const float*)d_in[1];
    const int*   eidx  = (const int*)d_in[2];
    const float* emask = (const float*)d_in[3];
    const float* We1   = (const float*)d_in[4];
    const float* be1   = (const float*)d_in[5];
    const float* We2   = (const float*)d_in[6];
    const float* be2   = (const float*)d_in[7];
    const float* Wn1   = (const float*)d_in[8];
    const float* bn1   = (const float*)d_in[9];
    const float* Wn2   = (const float*)d_in[10];
    const float* bn2   = (const float*)d_in[11];
    const float* Wc1   = (const float*)d_in[12];
    const float* bc1   = (const float*)d_in[13];
    const float* Wc2   = (const float*)d_in[14];

    float* hout = (float*)d_out;
    float* cout = hout + (size_t)N_NODES * 64;

    // ws layout
    char* p = (char*)d_ws;
    float* agg  = (float*)p;                      p += (size_t)N_NODES * 64 * 4; // 10.24 MB
    float* aggc = (float*)p;                      p += (size_t)N_NODES * 3 * 4;  // 0.48 MB
    int* hist   = (int*)p;                        p += (size_t)N_NODES * 4;      // 0.16 MB
    int* offs   = (int*)p;                        p += (size_t)N_NODES * 4;
    int* rank   = (int*)p;                        p += (size_t)N_EDGES * 4;      // 5.12 MB
    uint4* payload = (uint4*)p;                   p += (size_t)N_EDGES * 16;     // 20.48 MB
    unsigned short* h_bf = (unsigned short*)p;    p += (size_t)N_NODES * 64 * 2; // 5.12 MB
    float4* coord4 = (float4*)p;                  p += (size_t)N_NODES * 16;     // 0.64 MB
    unsigned short* Wt1  = (unsigned short*)p;    p += 8192 * 2;
    unsigned short* Wt2  = (unsigned short*)p;    p += 4096 * 2;
    unsigned short* Wtc1 = (unsigned short*)p;    p += 4096 * 2;
    unsigned short* Wtn1 = (unsigned short*)p;    p += 8192 * 2;
    unsigned short* Wtn2 = (unsigned short*)p;    p += 4096 * 2;

    hipMemsetAsync(hist, 0, (size_t)N_NODES * 4, stream);   // 160 KB only
    hist_rank_kernel<<<1519, 256, 0, stream>>>(eidx, coord, We1, We2, Wc1, Wn1, Wn2,
                                               hist, rank, coord4,
                                               Wt1, Wt2, Wtc1, Wtn1, Wtn2);
    scan_kernel<<<1, 1024, 0, stream>>>(hist, offs);
    scatter_prep_kernel<<<6368, 256, 0, stream>>>(eidx, emask, rank, offs, coord4,
                                                  payload, h, h_bf, agg);
    egcl_edge_mfma<<<N_EDGES / 256, 256, 0, stream>>>(
        h_bf, payload, offs, hist,
        We1, be1, be2, bc1, Wc2, Wt1, Wt2, Wtc1, agg, aggc);
    egcl_node_coord<<<NODE_BLOCKS + (N_NODES * 3 + 255) / 256, 256, 0, stream>>>(
        h_bf, agg, bn1, bn2, Wtn1, Wtn2, coord, aggc, hist, hout, cout);
}